// Round 1
// baseline (5659.440 us; speedup 1.0000x reference)
//
#include <hip/hip_runtime.h>
#include <hip/hip_bf16.h>
#include <cstdint>
#include <cstddef>

// ---------------------------------------------------------------------------
// DisentangledMultiHeadAttention: B=8, H=2, T=2048, D=2048, C=4096
//   q = x@Wq^T, k = x@Wk^T, v = x@Wv^T         (reshaped to (B,H,T,D))
//   scores = q@k^T / sqrt(D) + pos_bias[h,s]   (B,H,T,T)
//   atten  = softmax(scores, -1)                -> output 1 (2nd region)
//   y      = (atten@v) reshaped @ Wo^T          -> output 0 (1st region)
//
// All 4 GEMM families are NT (A: MxK row-major, B: NxK row-major) because we
// store v TRANSPOSED (d-major) in the projection epilogue.
// bf16 MFMA (16x16x32), fp32 accumulate. fp32 sources are converted to bf16
// (RNE) during register staging.
// ---------------------------------------------------------------------------

typedef short short8_t __attribute__((ext_vector_type(8)));
typedef float f32x4   __attribute__((ext_vector_type(4)));

__device__ __forceinline__ short f2bf(float f) {
  unsigned u = __builtin_bit_cast(unsigned, f);
  u = (u + 0x7FFFu + ((u >> 16) & 1u)) >> 16;   // round-to-nearest-even
  return (short)u;
}

__device__ __forceinline__ short8_t cvt8(float4 a, float4 b) {
  short8_t r;
  r[0] = f2bf(a.x); r[1] = f2bf(a.y); r[2] = f2bf(a.z); r[3] = f2bf(a.w);
  r[4] = f2bf(b.x); r[5] = f2bf(b.y); r[6] = f2bf(b.z); r[7] = f2bf(b.w);
  return r;
}

// MODE 0: q/k proj   A=x(f32,16384x4096)      B=W(f32,4096x4096)   C=bf16 (b,h,t,d)
// MODE 2: v proj     same inputs                                    C=bf16 (b,h,d,s)  [transposed]
// MODE 3: scores     A=qb(bf16, batch z)      B=kb(bf16, batch z)  C=f32 scores+bias -> d_out attn
// MODE 4: PV         A=attn(f32, batch z)     B=vT(bf16, batch z)  C=bf16 (b*T+t, h*D+d)
// MODE 5: out proj   A=yb(bf16,16384x4096)    B=Wo(f32)            C=f32 d_out
template<int MODE>
__global__ __launch_bounds__(256)
void gemm_nt(const void* __restrict__ Ag, const void* __restrict__ Bg,
             void* __restrict__ Cg, const float* __restrict__ bias) {
  constexpr bool A_F32 = (MODE <= 2) || (MODE == 4);
  constexpr bool B_F32 = (MODE <= 2) || (MODE == 5);
  constexpr int  K     = (MODE == 3 || MODE == 4) ? 2048 : 4096;

  __shared__ short As[128 * 32];
  __shared__ short Bs[128 * 32];

  const int tid = threadIdx.x;
  const int m0  = blockIdx.y * 128;
  const int n0  = blockIdx.x * 128;
  const int z   = blockIdx.z;

  size_t aoff = 0, boff = 0;
  if constexpr (MODE == 3 || MODE == 4) {
    aoff = (size_t)z << 22;   // 2048*2048 elements per (b,h)
    boff = (size_t)z << 22;
  }

  // staging: each thread moves 16 elements of A and 16 of B per K-step
  const int srow = tid >> 1;          // 0..127
  const int scol = (tid & 1) * 16;    // 0 or 16

  const int l  = tid & 63;
  const int wm = (tid >> 7) * 64;         // wave's M offset in tile
  const int wn = ((tid >> 6) & 1) * 64;   // wave's N offset in tile
  const int fr = l & 15;
  const int kg = (l >> 4) * 8;

  f32x4 acc[4][4] = {};

  for (int kt = 0; kt < K; kt += 32) {
    // ---- stage A tile (128 x 32) ----
    {
      size_t off = aoff + (size_t)(m0 + srow) * K + kt + scol;
      short* d = &As[srow * 32 + scol];
      if constexpr (A_F32) {
        const float4* p = (const float4*)((const float*)Ag + off);
        float4 x0 = p[0], x1 = p[1], x2 = p[2], x3 = p[3];
        *(short8_t*)(d)     = cvt8(x0, x1);
        *(short8_t*)(d + 8) = cvt8(x2, x3);
      } else {
        const uint4* p = (const uint4*)((const unsigned short*)Ag + off);
        uint4 u0 = p[0], u1 = p[1];
        *(uint4*)(d)     = u0;
        *(uint4*)(d + 8) = u1;
      }
    }
    // ---- stage B tile (128 x 32) ----
    {
      size_t off = boff + (size_t)(n0 + srow) * K + kt + scol;
      short* d = &Bs[srow * 32 + scol];
      if constexpr (B_F32) {
        const float4* p = (const float4*)((const float*)Bg + off);
        float4 x0 = p[0], x1 = p[1], x2 = p[2], x3 = p[3];
        *(short8_t*)(d)     = cvt8(x0, x1);
        *(short8_t*)(d + 8) = cvt8(x2, x3);
      } else {
        const uint4* p = (const uint4*)((const unsigned short*)Bg + off);
        uint4 u0 = p[0], u1 = p[1];
        *(uint4*)(d)     = u0;
        *(uint4*)(d + 8) = u1;
      }
    }
    __syncthreads();

    short8_t a[4], b[4];
#pragma unroll
    for (int i = 0; i < 4; ++i)
      a[i] = *(const short8_t*)&As[(wm + i * 16 + fr) * 32 + kg];
#pragma unroll
    for (int j = 0; j < 4; ++j)
      b[j] = *(const short8_t*)&Bs[(wn + j * 16 + fr) * 32 + kg];
#pragma unroll
    for (int i = 0; i < 4; ++i)
#pragma unroll
      for (int j = 0; j < 4; ++j)
        acc[i][j] = __builtin_amdgcn_mfma_f32_16x16x32_bf16(a[i], b[j], acc[i][j], 0, 0, 0);
    __syncthreads();
  }

  // ---- epilogue: C/D layout col=lane&15, row=(lane>>4)*4+reg ----
#pragma unroll
  for (int i = 0; i < 4; ++i) {
#pragma unroll
    for (int j = 0; j < 4; ++j) {
#pragma unroll
      for (int r = 0; r < 4; ++r) {
        const int gm = m0 + wm + i * 16 + (l >> 4) * 4 + r;
        const int gn = n0 + wn + j * 16 + fr;
        const float v = acc[i][j][r];
        if constexpr (MODE == 0) {
          // (b,t) x (h,d) -> qb[(b*2+h)][t][d]
          short* dst = (short*)Cg;
          const int bh = ((gm >> 11) << 1) + (gn >> 11);
          dst[((size_t)bh << 22) + ((size_t)(gm & 2047) << 11) + (gn & 2047)] = f2bf(v);
        } else if constexpr (MODE == 2) {
          // v transposed: vT[(b*2+h)][d][s], s = gm&2047 (sequence), d = gn&2047
          short* dst = (short*)Cg;
          const int bh = ((gm >> 11) << 1) + (gn >> 11);
          dst[((size_t)bh << 22) + ((size_t)(gn & 2047) << 11) + (gm & 2047)] = f2bf(v);
        } else if constexpr (MODE == 3) {
          // scores*scale + pos_bias[h][s]  (s = gn)
          float* dst = (float*)Cg;
          const float sv = v * 0.022097086912079608f + bias[((z & 1) << 11) + gn];
          dst[((size_t)z << 22) + ((size_t)gm << 11) + gn] = sv;
        } else if constexpr (MODE == 4) {
          // y reorder: yb[b*2048 + t][h*2048 + d]  (bf16, feeds Wo GEMM)
          short* dst = (short*)Cg;
          const size_t row = ((size_t)(z >> 1) << 11) + gm;
          dst[(row << 12) + ((size_t)(z & 1) << 11) + gn] = f2bf(v);
        } else {
          // MODE 5: final output fp32
          float* dst = (float*)Cg;
          dst[(size_t)gm * 4096 + gn] = v;
        }
      }
    }
  }
}

// row softmax in place over 2048-wide rows (32768 rows)
__global__ __launch_bounds__(256)
void softmax_rows(float* __restrict__ attn) {
  float* row = attn + ((size_t)blockIdx.x << 11);
  const int tid = threadIdx.x;

  float4 v0 = *(const float4*)(row + tid * 8);
  float4 v1 = *(const float4*)(row + tid * 8 + 4);

  float m = fmaxf(fmaxf(fmaxf(v0.x, v0.y), fmaxf(v0.z, v0.w)),
                  fmaxf(fmaxf(v1.x, v1.y), fmaxf(v1.z, v1.w)));
#pragma unroll
  for (int off = 1; off < 64; off <<= 1) m = fmaxf(m, __shfl_xor(m, off));

  __shared__ float redm[4];
  __shared__ float reds[4];
  if ((tid & 63) == 0) redm[tid >> 6] = m;
  __syncthreads();
  m = fmaxf(fmaxf(redm[0], redm[1]), fmaxf(redm[2], redm[3]));

  float e[8];
  e[0] = expf(v0.x - m); e[1] = expf(v0.y - m); e[2] = expf(v0.z - m); e[3] = expf(v0.w - m);
  e[4] = expf(v1.x - m); e[5] = expf(v1.y - m); e[6] = expf(v1.z - m); e[7] = expf(v1.w - m);
  float s = 0.f;
#pragma unroll
  for (int i = 0; i < 8; ++i) s += e[i];
#pragma unroll
  for (int off = 1; off < 64; off <<= 1) s += __shfl_xor(s, off);
  if ((tid & 63) == 0) reds[tid >> 6] = s;
  __syncthreads();
  s = reds[0] + reds[1] + reds[2] + reds[3];

  const float inv = 1.0f / s;
  float4 o0, o1;
  o0.x = e[0] * inv; o0.y = e[1] * inv; o0.z = e[2] * inv; o0.w = e[3] * inv;
  o1.x = e[4] * inv; o1.y = e[5] * inv; o1.z = e[6] * inv; o1.w = e[7] * inv;
  *(float4*)(row + tid * 8)     = o0;
  *(float4*)(row + tid * 8 + 4) = o1;
}

extern "C" void kernel_launch(void* const* d_in, const int* in_sizes, int n_in,
                              void* d_out, int out_size, void* d_ws, size_t ws_size,
                              hipStream_t stream) {
  const float* x  = (const float*)d_in[0];
  const float* Wq = (const float*)d_in[1];
  const float* Wk = (const float*)d_in[2];
  const float* Wv = (const float*)d_in[3];
  const float* Wo = (const float*)d_in[4];
  const float* pb = (const float*)d_in[5];

  float* y_out = (float*)d_out;                       // 8*2048*4096 f32
  float* attn  = y_out + (size_t)8 * 2048 * 4096;     // 8*2*2048*2048 f32

  // workspace: 4 x 64Mi bf16 buffers = 512 MB
  const size_t NEED = 4ull * 67108864ull * 2ull;
  if (ws_size < NEED) return;  // insufficient scratch (would be UB)
  short* qb  = (short*)d_ws;
  short* kb  = qb  + 67108864;   // (b,h,t,d)
  short* vtb = kb  + 67108864;   // (b,h,d,s)
  short* yb  = vtb + 67108864;   // (b*T+t, h*D+d)

  const dim3 blk(256);
  // projections: M=16384, N=4096 -> grid (32,128)
  gemm_nt<0><<<dim3(32, 128, 1), blk, 0, stream>>>(x, Wq, qb,  nullptr);
  gemm_nt<0><<<dim3(32, 128, 1), blk, 0, stream>>>(x, Wk, kb,  nullptr);
  gemm_nt<2><<<dim3(32, 128, 1), blk, 0, stream>>>(x, Wv, vtb, nullptr);
  // scores: per (b,h) 2048x2048, 16 batches
  gemm_nt<3><<<dim3(16, 16, 16), blk, 0, stream>>>(qb, kb, attn, pb);
  // softmax over key axis, in place (also final atten output)
  softmax_rows<<<dim3(32768), blk, 0, stream>>>(attn);
  // PV: per (b,h) 2048x2048
  gemm_nt<4><<<dim3(16, 16, 16), blk, 0, stream>>>(attn, vtb, yb, nullptr);
  // output projection -> d_out
  gemm_nt<5><<<dim3(32, 128, 1), blk, 0, stream>>>(yb, Wo, y_out, nullptr);
}

// Round 2
// 3821.178 us; speedup vs baseline: 1.4811x; 1.4811x over previous
//
#include <hip/hip_runtime.h>
#include <hip/hip_bf16.h>
#include <cstdint>
#include <cstddef>

// ---------------------------------------------------------------------------
// DisentangledMultiHeadAttention: B=8, H=2, T=2048, D=2048, C=4096
// All-bf16 MFMA pipeline:
//   cvt x, W* -> bf16 once (pure-BW), then every GEMM is bf16 NT with
//   global_load_lds width-16 staging (m97 structure, 128x128x32 tile).
//   v stored TRANSPOSED so PV is NT; softmax emits bf16 probs for PV.
// Workspace (512 MB = 4 x 128 MB):
//   buf0: xb        -> (after projections) wob
//   buf1: qb        -> (after scores)      attn_bf
//   buf2: kb        -> (after scores)      yb
//   buf3: vtb
//   W-bf16 staging for Wq/Wk/Wv lives in d_out's attn region (dead until
//   the scores GEMM overwrites it).
// ---------------------------------------------------------------------------

typedef short short8_t __attribute__((ext_vector_type(8)));
typedef float f32x4   __attribute__((ext_vector_type(4)));

__device__ __forceinline__ short f2bf(float f) {
  unsigned u = __builtin_bit_cast(unsigned, f);
  u = (u + 0x7FFFu + ((u >> 16) & 1u)) >> 16;   // round-to-nearest-even
  return (short)u;
}

__device__ __forceinline__ short8_t cvt8(float4 a, float4 b) {
  short8_t r;
  r[0] = f2bf(a.x); r[1] = f2bf(a.y); r[2] = f2bf(a.z); r[3] = f2bf(a.w);
  r[4] = f2bf(b.x); r[5] = f2bf(b.y); r[6] = f2bf(b.z); r[7] = f2bf(b.w);
  return r;
}

// async 16B global->LDS (LDS dest must be wave-uniform base + lane*16)
__device__ __forceinline__ void gld_lds16(const void* g, void* l) {
  __builtin_amdgcn_global_load_lds(
      (const __attribute__((address_space(1))) void*)g,
      (__attribute__((address_space(3))) void*)l, 16, 0, 0);
}

// fp32 -> bf16 bulk convert, 8 elem/thread, grid-stride
__global__ __launch_bounds__(256)
void cvt_f32_bf16(const float* __restrict__ src, short* __restrict__ dst, int n8) {
  for (int i = blockIdx.x * blockDim.x + threadIdx.x; i < n8;
       i += gridDim.x * blockDim.x) {
    const float4* p = (const float4*)(src + (size_t)i * 8);
    float4 a = p[0], b = p[1];
    *(short8_t*)(dst + (size_t)i * 8) = cvt8(a, b);
  }
}

// MODE 0: q/k proj  C=bf16 (b,h,t,d)        K=4096
// MODE 2: v proj    C=bf16 (b,h,d,s) [T]    K=4096
// MODE 3: scores    C=f32 scale+bias -> attn (d_out)   K=2048, batched z
// MODE 4: PV        C=bf16 (b*T+t, h*D+d)   K=2048, batched z
// MODE 5: out proj  C=f32 d_out y           K=4096
template<int MODE>
__global__ __launch_bounds__(256)
void gemm_nt(const short* __restrict__ Ag, const short* __restrict__ Bg,
             void* __restrict__ Cg, const float* __restrict__ bias) {
  constexpr int K = (MODE == 3 || MODE == 4) ? 2048 : 4096;

  __shared__ short As[128 * 32];
  __shared__ short Bs[128 * 32];

  const int tid = threadIdx.x;
  const int m0  = blockIdx.y * 128;
  const int n0  = blockIdx.x * 128;
  const int z   = blockIdx.z;

  size_t aoff = 0, boff = 0;
  if constexpr (MODE == 3 || MODE == 4) {
    aoff = (size_t)z << 22;
    boff = (size_t)z << 22;
  }

  // staging: 512 chunks of 16B per tile; chunk c -> LDS byte c*16 (linear,
  // required by global_load_lds); global source slot is XOR-swizzled with
  // row&3 so the fragment ds_read_b128 is 4-way instead of 8-way conflicted.
  const int c0 = tid, c1 = tid + 256;
  const int r0 = c0 >> 2, r1 = c1 >> 2;
  const int s0 = (((c0 & 3) ^ (r0 & 3)) << 3);   // source slot, elements
  const int s1 = (((c1 & 3) ^ (r1 & 3)) << 3);

  const int l  = tid & 63;
  const int wm = (tid >> 7) << 6;         // wave M offset (0/64)
  const int wn = ((tid >> 6) & 1) << 6;   // wave N offset (0/64)
  const int fr = l & 15;
  const int kq = l >> 4;                  // k-quarter 0..3

  const short* Arow0 = Ag + aoff + (size_t)(m0 + r0) * K + s0;
  const short* Arow1 = Ag + aoff + (size_t)(m0 + r1) * K + s1;
  const short* Brow0 = Bg + boff + (size_t)(n0 + r0) * K + s0;
  const short* Brow1 = Bg + boff + (size_t)(n0 + r1) * K + s1;

  f32x4 acc[4][4] = {};

  for (int kt = 0; kt < K; kt += 32) {
    gld_lds16(Arow0 + kt, &As[c0 << 3]);
    gld_lds16(Arow1 + kt, &As[c1 << 3]);
    gld_lds16(Brow0 + kt, &Bs[c0 << 3]);
    gld_lds16(Brow1 + kt, &Bs[c1 << 3]);
    __syncthreads();   // drains vmcnt before LDS reads

    short8_t a[4], b[4];
#pragma unroll
    for (int i = 0; i < 4; ++i) {
      const int row = wm + i * 16 + fr;
      a[i] = *(const short8_t*)&As[row * 32 + ((kq ^ (row & 3)) << 3)];
    }
#pragma unroll
    for (int j = 0; j < 4; ++j) {
      const int row = wn + j * 16 + fr;
      b[j] = *(const short8_t*)&Bs[row * 32 + ((kq ^ (row & 3)) << 3)];
    }
#pragma unroll
    for (int i = 0; i < 4; ++i)
#pragma unroll
      for (int j = 0; j < 4; ++j)
        acc[i][j] = __builtin_amdgcn_mfma_f32_16x16x32_bf16(a[i], b[j], acc[i][j], 0, 0, 0);
    __syncthreads();
  }

  // epilogue: C/D layout col=lane&15, row=(lane>>4)*4+reg
#pragma unroll
  for (int i = 0; i < 4; ++i) {
#pragma unroll
    for (int j = 0; j < 4; ++j) {
#pragma unroll
      for (int r = 0; r < 4; ++r) {
        const int gm = m0 + wm + i * 16 + (l >> 4) * 4 + r;
        const int gn = n0 + wn + j * 16 + fr;
        const float v = acc[i][j][r];
        if constexpr (MODE == 0) {
          short* dst = (short*)Cg;
          const int bh = ((gm >> 11) << 1) + (gn >> 11);
          dst[((size_t)bh << 22) + ((size_t)(gm & 2047) << 11) + (gn & 2047)] = f2bf(v);
        } else if constexpr (MODE == 2) {
          short* dst = (short*)Cg;
          const int bh = ((gm >> 11) << 1) + (gn >> 11);
          dst[((size_t)bh << 22) + ((size_t)(gn & 2047) << 11) + (gm & 2047)] = f2bf(v);
        } else if constexpr (MODE == 3) {
          float* dst = (float*)Cg;
          const float sv = v * 0.022097086912079608f + bias[((z & 1) << 11) + gn];
          dst[((size_t)z << 22) + ((size_t)gm << 11) + gn] = sv;
        } else if constexpr (MODE == 4) {
          short* dst = (short*)Cg;
          const size_t row = ((size_t)(z >> 1) << 11) + gm;
          dst[(row << 12) + ((size_t)(z & 1) << 11) + gn] = f2bf(v);
        } else {
          float* dst = (float*)Cg;
          dst[(size_t)gm * 4096 + gn] = v;
        }
      }
    }
  }
}

// row softmax in place (fp32, 2048 wide) + bf16 copy for the PV GEMM
__global__ __launch_bounds__(256)
void softmax_rows(float* __restrict__ attn, short* __restrict__ outb) {
  float* row  = attn + ((size_t)blockIdx.x << 11);
  short* rowb = outb + ((size_t)blockIdx.x << 11);
  const int tid = threadIdx.x;

  float4 v0 = *(const float4*)(row + tid * 8);
  float4 v1 = *(const float4*)(row + tid * 8 + 4);

  float m = fmaxf(fmaxf(fmaxf(v0.x, v0.y), fmaxf(v0.z, v0.w)),
                  fmaxf(fmaxf(v1.x, v1.y), fmaxf(v1.z, v1.w)));
#pragma unroll
  for (int off = 1; off < 64; off <<= 1) m = fmaxf(m, __shfl_xor(m, off));

  __shared__ float redm[4];
  __shared__ float reds[4];
  if ((tid & 63) == 0) redm[tid >> 6] = m;
  __syncthreads();
  m = fmaxf(fmaxf(redm[0], redm[1]), fmaxf(redm[2], redm[3]));

  float e[8];
  e[0] = expf(v0.x - m); e[1] = expf(v0.y - m); e[2] = expf(v0.z - m); e[3] = expf(v0.w - m);
  e[4] = expf(v1.x - m); e[5] = expf(v1.y - m); e[6] = expf(v1.z - m); e[7] = expf(v1.w - m);
  float s = 0.f;
#pragma unroll
  for (int i = 0; i < 8; ++i) s += e[i];
#pragma unroll
  for (int off = 1; off < 64; off <<= 1) s += __shfl_xor(s, off);
  if ((tid & 63) == 0) reds[tid >> 6] = s;
  __syncthreads();
  s = reds[0] + reds[1] + reds[2] + reds[3];

  const float inv = 1.0f / s;
  float4 o0, o1;
  o0.x = e[0] * inv; o0.y = e[1] * inv; o0.z = e[2] * inv; o0.w = e[3] * inv;
  o1.x = e[4] * inv; o1.y = e[5] * inv; o1.z = e[6] * inv; o1.w = e[7] * inv;
  *(float4*)(row + tid * 8)     = o0;
  *(float4*)(row + tid * 8 + 4) = o1;
  *(short8_t*)(rowb + tid * 8)  = cvt8(o0, o1);
}

extern "C" void kernel_launch(void* const* d_in, const int* in_sizes, int n_in,
                              void* d_out, int out_size, void* d_ws, size_t ws_size,
                              hipStream_t stream) {
  const float* x  = (const float*)d_in[0];
  const float* Wq = (const float*)d_in[1];
  const float* Wk = (const float*)d_in[2];
  const float* Wv = (const float*)d_in[3];
  const float* Wo = (const float*)d_in[4];
  const float* pb = (const float*)d_in[5];

  float* y_out = (float*)d_out;                       // 8*2048*4096 f32
  float* attn  = y_out + (size_t)8 * 2048 * 4096;     // 16*2048*2048 f32

  const size_t NEED = 4ull * 67108864ull * 2ull;      // 512 MB
  if (ws_size < NEED) return;
  short* buf0 = (short*)d_ws;
  short* buf1 = buf0 + 67108864;
  short* buf2 = buf1 + 67108864;
  short* buf3 = buf2 + 67108864;

  short* xb      = buf0;             // x bf16 (16384 x 4096)
  short* qb      = buf1;             // (b,h,t,d)
  short* kb      = buf2;             // (b,h,t,d)
  short* vtb     = buf3;             // (b,h,d,s)
  short* wob     = buf0;             // Wo bf16 (reuses xb after projections)
  short* attn_bf = buf1;             // bf16 probs (reuses qb after scores)
  short* yb      = buf2;             // attn@v bf16 (reuses kb after scores)
  short* wb      = (short*)attn;     // W staging in d_out attn region (32 MB
                                     // of 256 MB; dead until scores GEMM)

  const dim3 blk(256);
  const dim3 gcv(2048);

  cvt_f32_bf16<<<gcv, blk, 0, stream>>>(x, xb, 67108864 / 8);

  cvt_f32_bf16<<<gcv, blk, 0, stream>>>(Wq, wb, 16777216 / 8);
  gemm_nt<0><<<dim3(32, 128, 1), blk, 0, stream>>>(xb, wb, qb, nullptr);
  cvt_f32_bf16<<<gcv, blk, 0, stream>>>(Wk, wb, 16777216 / 8);
  gemm_nt<0><<<dim3(32, 128, 1), blk, 0, stream>>>(xb, wb, kb, nullptr);
  cvt_f32_bf16<<<gcv, blk, 0, stream>>>(Wv, wb, 16777216 / 8);
  gemm_nt<2><<<dim3(32, 128, 1), blk, 0, stream>>>(xb, wb, vtb, nullptr);

  cvt_f32_bf16<<<gcv, blk, 0, stream>>>(Wo, wob, 16777216 / 8);  // x dead now

  gemm_nt<3><<<dim3(16, 16, 16), blk, 0, stream>>>(qb, kb, attn, pb);
  softmax_rows<<<dim3(32768), blk, 0, stream>>>(attn, attn_bf);
  gemm_nt<4><<<dim3(16, 16, 16), blk, 0, stream>>>(attn_bf, vtb, yb, nullptr);
  gemm_nt<5><<<dim3(32, 128, 1), blk, 0, stream>>>(yb, wob, y_out, nullptr);
}

// Round 3
// 3011.124 us; speedup vs baseline: 1.8795x; 1.2690x over previous
//
#include <hip/hip_runtime.h>
#include <hip/hip_bf16.h>
#include <cstdint>
#include <cstddef>

// ---------------------------------------------------------------------------
// DisentangledMultiHeadAttention: B=8, H=2, T=2048, D=2048, C=4096
// 256x256-tile bf16 MFMA GEMM engine, 8 waves (2M x 4N), K-slab ring pipeline:
//   LDS = ring of 4 slabs (K=32 each): A[256][32] + B[256][32] = 32KB/slab,
//   128KB total. Per phase: stage slab p+3 (4x global_load_lds dwordx4),
//   s_waitcnt vmcnt(12) [3 slabs in flight -- never drained to 0],
//   s_barrier, 12x ds_read_b128 (2-way-swizzled), 32x mfma_16x16x32_bf16,
//   s_barrier. T1 XCD swizzle + T5 setprio.
// LDS read swizzle: phys slot = kq ^ ((row>>1)&3)  -> 2 lanes/bank (free).
// Source side pre-applies the same involution (both-sides rule).
// v stored TRANSPOSED so PV is NT; softmax emits bf16 probs for PV.
// ---------------------------------------------------------------------------

typedef short short8_t __attribute__((ext_vector_type(8)));
typedef float f32x4   __attribute__((ext_vector_type(4)));

__device__ __forceinline__ short f2bf(float f) {
  unsigned u = __builtin_bit_cast(unsigned, f);
  u = (u + 0x7FFFu + ((u >> 16) & 1u)) >> 16;   // round-to-nearest-even
  return (short)u;
}

__device__ __forceinline__ short8_t cvt8(float4 a, float4 b) {
  short8_t r;
  r[0] = f2bf(a.x); r[1] = f2bf(a.y); r[2] = f2bf(a.z); r[3] = f2bf(a.w);
  r[4] = f2bf(b.x); r[5] = f2bf(b.y); r[6] = f2bf(b.z); r[7] = f2bf(b.w);
  return r;
}

__device__ __forceinline__ void gld_lds16(const void* g, void* l) {
  __builtin_amdgcn_global_load_lds(
      (const __attribute__((address_space(1))) void*)g,
      (__attribute__((address_space(3))) void*)l, 16, 0, 0);
}

// fp32 -> bf16 bulk convert, 8 elem/thread, grid-stride
__global__ __launch_bounds__(256)
void cvt_f32_bf16(const float* __restrict__ src, short* __restrict__ dst, int n8) {
  for (int i = blockIdx.x * blockDim.x + threadIdx.x; i < n8;
       i += gridDim.x * blockDim.x) {
    const float4* p = (const float4*)(src + (size_t)i * 8);
    float4 a = p[0], b = p[1];
    *(short8_t*)(dst + (size_t)i * 8) = cvt8(a, b);
  }
}

// MODE 0: q/k proj  C=bf16 (b,h,t,d)                 K=4096
// MODE 2: v proj    C=bf16 (b,h,d,s) [transposed]    K=4096
// MODE 3: scores    C=f32 scale+bias -> attn (d_out) K=2048, batched z
// MODE 4: PV        C=bf16 (b*T+t, h*D+d)            K=2048, batched z
// MODE 5: out proj  C=f32 y (d_out)                  K=4096
template<int MODE>
__global__ __launch_bounds__(512, 2)
void gemm256(const short* __restrict__ Ag, const short* __restrict__ Bg,
             void* __restrict__ Cg, const float* __restrict__ bias) {
  constexpr int K  = (MODE == 3 || MODE == 4) ? 2048 : 4096;
  constexpr int NS = K / 32;   // number of K-slabs

  __shared__ short lds[65536];  // 4 slots x (A 8192 + B 8192 shorts) = 128KB

  const int tid = threadIdx.x;

  // T1: bijective XCD swizzle (gridDim.x = 1024, divisible by 8)
  const int bid = blockIdx.x;
  const int id  = (bid & 7) * (gridDim.x >> 3) + (bid >> 3);

  int m0, n0, z = 0;
  size_t aoff = 0, boff = 0;
  if constexpr (MODE == 3 || MODE == 4) {
    z  = id >> 6;                       // 16 batches
    m0 = ((id >> 3) & 7) << 8;          // 8 m-tiles
    n0 = (id & 7) << 8;                 // 8 n-tiles
    aoff = boff = (size_t)z << 22;
  } else {
    m0 = (id >> 4) << 8;                // 64 m-tiles
    n0 = (id & 15) << 8;                // 16 n-tiles (n fastest: A-panel reuse)
  }

  // ---- staging setup: slab = 1024 chunks of 16B; thread does chunks
  //      tid and tid+512 for each operand. chunk c -> row c>>2, phys slot c&3.
  //      Global source slot = phys ^ ((row>>1)&3)  [inverse swizzle].
  const int r0 = tid >> 2;
  const int qs = ((tid & 3) ^ ((r0 >> 1) & 3)) << 3;   // element offset in row
  const short* Ap0 = Ag + aoff + (size_t)(m0 + r0) * K + qs;
  const short* Ap1 = Ap0 + (size_t)128 * K;            // row r0+128, same swz
  const short* Bp0 = Bg + boff + (size_t)(n0 + r0) * K + qs;
  const short* Bp1 = Bp0 + (size_t)128 * K;
  short* la0 = &lds[0]    + tid * 8;   // + slot*16384
  short* la1 = la0 + 4096;             // chunk tid+512
  short* lb0 = &lds[8192] + tid * 8;
  short* lb1 = lb0 + 4096;

  auto STAGE = [&](int t) {
    const int s = (t & 3) * 16384;
    const int k = t * 32;
    gld_lds16(Ap0 + k, la0 + s);
    gld_lds16(Ap1 + k, la1 + s);
    gld_lds16(Bp0 + k, lb0 + s);
    gld_lds16(Bp1 + k, lb1 + s);
  };

  // ---- fragment read setup (2-way-conflict swizzled) ----
  const int l  = tid & 63;
  const int fr = l & 15;
  const int kq = l >> 4;
  const int wm = (tid >> 8) << 7;         // wave m offset: 0 / 128
  const int wn = ((tid >> 6) & 3) << 6;   // wave n offset: 0/64/128/192
  const int slotP = (kq ^ ((fr >> 1) & 3)) << 3;
  const int aB = (wm + fr) * 32 + slotP;
  const int bB = 8192 + (wn + fr) * 32 + slotP;

  f32x4 acc[8][4] = {};

  STAGE(0); STAGE(1); STAGE(2);

  for (int p = 0; p < NS; ++p) {
    if (p + 3 < NS) {
      STAGE(p + 3);
      asm volatile("s_waitcnt vmcnt(12)" ::: "memory");  // slab p landed
    } else if (p + 2 < NS) {
      asm volatile("s_waitcnt vmcnt(8)" ::: "memory");
    } else if (p + 1 < NS) {
      asm volatile("s_waitcnt vmcnt(4)" ::: "memory");
    } else {
      asm volatile("s_waitcnt vmcnt(0)" ::: "memory");
    }
    __builtin_amdgcn_s_barrier();          // slab p visible to all waves
    __builtin_amdgcn_sched_barrier(0);     // no LDS reads above the barrier

    const short* sl = &lds[(p & 3) * 16384];
    short8_t af[8], bf[4];
#pragma unroll
    for (int m = 0; m < 8; ++m) af[m] = *(const short8_t*)&sl[aB + m * 512];
#pragma unroll
    for (int n = 0; n < 4; ++n) bf[n] = *(const short8_t*)&sl[bB + n * 512];
    __builtin_amdgcn_s_setprio(1);
#pragma unroll
    for (int m = 0; m < 8; ++m)
#pragma unroll
      for (int n = 0; n < 4; ++n)
        acc[m][n] = __builtin_amdgcn_mfma_f32_16x16x32_bf16(af[m], bf[n], acc[m][n], 0, 0, 0);
    __builtin_amdgcn_s_setprio(0);
    __builtin_amdgcn_sched_barrier(0);
    __builtin_amdgcn_s_barrier();          // all reads of slab p done ->
                                           // next phase may overwrite slot p&3
  }

  // ---- epilogue: C/D frag layout col=lane&15, row=kq*4+r ----
#pragma unroll
  for (int m = 0; m < 8; ++m) {
#pragma unroll
    for (int n = 0; n < 4; ++n) {
#pragma unroll
      for (int r = 0; r < 4; ++r) {
        const int gm = m0 + wm + m * 16 + kq * 4 + r;
        const int gn = n0 + wn + n * 16 + fr;
        const float v = acc[m][n][r];
        if constexpr (MODE == 0) {
          short* dst = (short*)Cg;
          const int bh = ((gm >> 11) << 1) + (gn >> 11);
          dst[((size_t)bh << 22) + ((size_t)(gm & 2047) << 11) + (gn & 2047)] = f2bf(v);
        } else if constexpr (MODE == 2) {
          short* dst = (short*)Cg;
          const int bh = ((gm >> 11) << 1) + (gn >> 11);
          dst[((size_t)bh << 22) + ((size_t)(gn & 2047) << 11) + (gm & 2047)] = f2bf(v);
        } else if constexpr (MODE == 3) {
          float* dst = (float*)Cg;
          const float sv = v * 0.022097086912079608f + bias[((z & 1) << 11) + gn];
          dst[((size_t)z << 22) + ((size_t)gm << 11) + gn] = sv;
        } else if constexpr (MODE == 4) {
          short* dst = (short*)Cg;
          const size_t row = ((size_t)(z >> 1) << 11) + gm;
          dst[(row << 12) + ((size_t)(z & 1) << 11) + gn] = f2bf(v);
        } else {
          float* dst = (float*)Cg;
          dst[(size_t)gm * 4096 + gn] = v;
        }
      }
    }
  }
}

// row softmax in place (fp32, 2048 wide) + bf16 copy for the PV GEMM
__global__ __launch_bounds__(256)
void softmax_rows(float* __restrict__ attn, short* __restrict__ outb) {
  float* row  = attn + ((size_t)blockIdx.x << 11);
  short* rowb = outb + ((size_t)blockIdx.x << 11);
  const int tid = threadIdx.x;

  float4 v0 = *(const float4*)(row + tid * 8);
  float4 v1 = *(const float4*)(row + tid * 8 + 4);

  float m = fmaxf(fmaxf(fmaxf(v0.x, v0.y), fmaxf(v0.z, v0.w)),
                  fmaxf(fmaxf(v1.x, v1.y), fmaxf(v1.z, v1.w)));
#pragma unroll
  for (int off = 1; off < 64; off <<= 1) m = fmaxf(m, __shfl_xor(m, off));

  __shared__ float redm[4];
  __shared__ float reds[4];
  if ((tid & 63) == 0) redm[tid >> 6] = m;
  __syncthreads();
  m = fmaxf(fmaxf(redm[0], redm[1]), fmaxf(redm[2], redm[3]));

  float e[8];
  e[0] = expf(v0.x - m); e[1] = expf(v0.y - m); e[2] = expf(v0.z - m); e[3] = expf(v0.w - m);
  e[4] = expf(v1.x - m); e[5] = expf(v1.y - m); e[6] = expf(v1.z - m); e[7] = expf(v1.w - m);
  float s = 0.f;
#pragma unroll
  for (int i = 0; i < 8; ++i) s += e[i];
#pragma unroll
  for (int off = 1; off < 64; off <<= 1) s += __shfl_xor(s, off);
  if ((tid & 63) == 0) reds[tid >> 6] = s;
  __syncthreads();
  s = reds[0] + reds[1] + reds[2] + reds[3];

  const float inv = 1.0f / s;
  float4 o0, o1;
  o0.x = e[0] * inv; o0.y = e[1] * inv; o0.z = e[2] * inv; o0.w = e[3] * inv;
  o1.x = e[4] * inv; o1.y = e[5] * inv; o1.z = e[6] * inv; o1.w = e[7] * inv;
  *(float4*)(row + tid * 8)     = o0;
  *(float4*)(row + tid * 8 + 4) = o1;
  *(short8_t*)(rowb + tid * 8)  = cvt8(o0, o1);
}

extern "C" void kernel_launch(void* const* d_in, const int* in_sizes, int n_in,
                              void* d_out, int out_size, void* d_ws, size_t ws_size,
                              hipStream_t stream) {
  const float* x  = (const float*)d_in[0];
  const float* Wq = (const float*)d_in[1];
  const float* Wk = (const float*)d_in[2];
  const float* Wv = (const float*)d_in[3];
  const float* Wo = (const float*)d_in[4];
  const float* pb = (const float*)d_in[5];

  float* y_out = (float*)d_out;                       // 8*2048*4096 f32
  float* attn  = y_out + (size_t)8 * 2048 * 4096;     // 16*2048*2048 f32

  const size_t NEED = 4ull * 67108864ull * 2ull;      // 512 MB
  if (ws_size < NEED) return;
  short* buf0 = (short*)d_ws;
  short* buf1 = buf0 + 67108864;
  short* buf2 = buf1 + 67108864;
  short* buf3 = buf2 + 67108864;

  short* xb      = buf0;             // x bf16 (16384 x 4096)
  short* qb      = buf1;             // (b,h,t,d)
  short* kb      = buf2;             // (b,h,t,d)
  short* vtb     = buf3;             // (b,h,d,s)
  short* wob     = buf0;             // Wo bf16 (reuses xb after projections)
  short* attn_bf = buf1;             // bf16 probs (reuses qb after scores)
  short* yb      = buf2;             // attn@v bf16 (reuses kb after scores)
  short* wb      = (short*)attn;     // W staging in d_out attn region
                                     // (dead until scores GEMM writes it)

  const dim3 blk512(512);
  const dim3 blk(256);
  const dim3 gcv(2048);
  const dim3 g1k(1024);

  cvt_f32_bf16<<<gcv, blk, 0, stream>>>(x, xb, 67108864 / 8);

  cvt_f32_bf16<<<gcv, blk, 0, stream>>>(Wq, wb, 16777216 / 8);
  gemm256<0><<<g1k, blk512, 0, stream>>>(xb, wb, qb, nullptr);
  cvt_f32_bf16<<<gcv, blk, 0, stream>>>(Wk, wb, 16777216 / 8);
  gemm256<0><<<g1k, blk512, 0, stream>>>(xb, wb, kb, nullptr);
  cvt_f32_bf16<<<gcv, blk, 0, stream>>>(Wv, wb, 16777216 / 8);
  gemm256<2><<<g1k, blk512, 0, stream>>>(xb, wb, vtb, nullptr);

  cvt_f32_bf16<<<gcv, blk, 0, stream>>>(Wo, wob, 16777216 / 8);  // x dead now

  gemm256<3><<<g1k, blk512, 0, stream>>>(qb, kb, attn, pb);
  softmax_rows<<<dim3(32768), blk, 0, stream>>>(attn, attn_bf);
  gemm256<4><<<g1k, blk512, 0, stream>>>(attn_bf, vtb, yb, nullptr);
  gemm256<5><<<g1k, blk512, 0, stream>>>(yb, wob, y_out, nullptr);
}

// Round 4
// 2924.675 us; speedup vs baseline: 1.9351x; 1.0296x over previous
//
#include <hip/hip_runtime.h>
#include <hip/hip_bf16.h>
#include <cstdint>
#include <cstddef>

// ---------------------------------------------------------------------------
// DisentangledMultiHeadAttention: B=8, H=2, T=2048, D=2048, C=4096
// 256x256-tile bf16 MFMA GEMM, 8 waves (2M x 4N), K-slab ring (4 x K=32 slabs,
// 128KB LDS) + REGISTER fragment double-buffer:
//   phase p: STAGE(p+3); vmcnt(8) [slab p+1 landed]; barrier;
//            ds_read slab p+1 frags -> nxt regs (overlaps MFMA below);
//            32x mfma(cur regs); barrier.
// LDS read swizzle (2-way, free): phys slot = kq ^ ((row>>1)&3), source side
// pre-applies the same involution (both-sides rule).
// v stored TRANSPOSED so PV is NT; softmax emits bf16 probs for PV.
// ---------------------------------------------------------------------------

typedef short short8_t __attribute__((ext_vector_type(8)));
typedef float f32x4   __attribute__((ext_vector_type(4)));

__device__ __forceinline__ short f2bf(float f) {
  unsigned u = __builtin_bit_cast(unsigned, f);
  u = (u + 0x7FFFu + ((u >> 16) & 1u)) >> 16;   // round-to-nearest-even
  return (short)u;
}

__device__ __forceinline__ short8_t cvt8(float4 a, float4 b) {
  short8_t r;
  r[0] = f2bf(a.x); r[1] = f2bf(a.y); r[2] = f2bf(a.z); r[3] = f2bf(a.w);
  r[4] = f2bf(b.x); r[5] = f2bf(b.y); r[6] = f2bf(b.z); r[7] = f2bf(b.w);
  return r;
}

__device__ __forceinline__ void gld_lds16(const void* g, void* l) {
  __builtin_amdgcn_global_load_lds(
      (const __attribute__((address_space(1))) void*)g,
      (__attribute__((address_space(3))) void*)l, 16, 0, 0);
}

// fp32 -> bf16 bulk convert, 8 elem/thread, grid-stride
__global__ __launch_bounds__(256)
void cvt_f32_bf16(const float* __restrict__ src, short* __restrict__ dst, int n8) {
  for (int i = blockIdx.x * blockDim.x + threadIdx.x; i < n8;
       i += gridDim.x * blockDim.x) {
    const float4* p = (const float4*)(src + (size_t)i * 8);
    float4 a = p[0], b = p[1];
    *(short8_t*)(dst + (size_t)i * 8) = cvt8(a, b);
  }
}

// MODE 0: q/k proj  C=bf16 (b,h,t,d)                 K=4096
// MODE 2: v proj    C=bf16 (b,h,d,s) [transposed]    K=4096
// MODE 3: scores    C=f32 scale+bias -> attn (d_out) K=2048, batched z
// MODE 4: PV        C=bf16 (b*T+t, h*D+d)            K=2048, batched z
// MODE 5: out proj  C=f32 y (d_out)                  K=4096
template<int MODE>
__global__ __launch_bounds__(512, 2)
void gemm256(const short* __restrict__ Ag, const short* __restrict__ Bg,
             void* __restrict__ Cg, const float* __restrict__ bias) {
  constexpr int K  = (MODE == 3 || MODE == 4) ? 2048 : 4096;
  constexpr int NS = K / 32;   // number of K-slabs (even)

  __shared__ short lds[65536];  // 4 slots x (A 8192 + B 8192 shorts) = 128KB

  const int tid = threadIdx.x;

  // T1: bijective XCD swizzle (gridDim.x = 1024, divisible by 8)
  const int bid = blockIdx.x;
  const int id  = (bid & 7) * (gridDim.x >> 3) + (bid >> 3);

  int m0, n0, z = 0;
  size_t aoff = 0, boff = 0;
  if constexpr (MODE == 3 || MODE == 4) {
    z  = id >> 6;                       // 16 batches
    m0 = ((id >> 3) & 7) << 8;          // 8 m-tiles
    n0 = (id & 7) << 8;                 // 8 n-tiles
    aoff = boff = (size_t)z << 22;
  } else {
    m0 = (id >> 4) << 8;                // 64 m-tiles
    n0 = (id & 15) << 8;                // 16 n-tiles (n fastest: A-panel reuse)
  }

  // ---- staging: slab = 1024 chunks of 16B; thread does chunks tid, tid+512
  //      per operand. chunk c -> row c>>2, phys slot c&3; global source slot
  //      = phys ^ ((row>>1)&3)  [inverse swizzle, both-sides rule].
  const int r0 = tid >> 2;
  const int qs = ((tid & 3) ^ ((r0 >> 1) & 3)) << 3;
  const short* Ap0 = Ag + aoff + (size_t)(m0 + r0) * K + qs;
  const short* Ap1 = Ap0 + (size_t)128 * K;
  const short* Bp0 = Bg + boff + (size_t)(n0 + r0) * K + qs;
  const short* Bp1 = Bp0 + (size_t)128 * K;
  short* la0 = &lds[0]    + tid * 8;
  short* la1 = la0 + 4096;
  short* lb0 = &lds[8192] + tid * 8;
  short* lb1 = lb0 + 4096;

  auto STAGE = [&](int t) {
    const int s = (t & 3) * 16384;
    const int k = t * 32;
    gld_lds16(Ap0 + k, la0 + s);
    gld_lds16(Ap1 + k, la1 + s);
    gld_lds16(Bp0 + k, lb0 + s);
    gld_lds16(Bp1 + k, lb1 + s);
  };

  // ---- fragment read setup (2-way-conflict swizzled) ----
  const int l  = tid & 63;
  const int fr = l & 15;
  const int kq = l >> 4;
  const int wm = (tid >> 8) << 7;         // wave m offset: 0 / 128
  const int wn = ((tid >> 6) & 3) << 6;   // wave n offset: 0/64/128/192
  const int slotP = (kq ^ ((fr >> 1) & 3)) << 3;
  const int aB = (wm + fr) * 32 + slotP;
  const int bB = 8192 + (wn + fr) * 32 + slotP;

  f32x4 acc[8][4] = {};
  short8_t fA[8], fB[4], gA[8], gB[4];

  // phase p: stage p+3, wait slab p+1 landed, barrier, prefetch slab p+1
  // frags into nxt regs (overlaps MFMA), MFMA slab p from cur regs, barrier.
  auto phase = [&](int p, short8_t (&cA)[8], short8_t (&cB)[4],
                   short8_t (&nA)[8], short8_t (&nB)[4]) {
    if (p + 3 < NS) {
      STAGE(p + 3);
      asm volatile("s_waitcnt vmcnt(8)" ::: "memory");   // slab p+1 landed
    } else if (p + 2 < NS) {
      asm volatile("s_waitcnt vmcnt(4)" ::: "memory");
    } else if (p + 1 < NS) {
      asm volatile("s_waitcnt vmcnt(0)" ::: "memory");
    }
    __builtin_amdgcn_s_barrier();          // slab p+1 visible; WAR: all waves
                                           // finished prev phase (see below)
    if (p + 1 < NS) {
      const short* sl = &lds[((p + 1) & 3) * 16384];
#pragma unroll
      for (int m = 0; m < 8; ++m) nA[m] = *(const short8_t*)&sl[aB + m * 512];
#pragma unroll
      for (int n = 0; n < 4; ++n) nB[n] = *(const short8_t*)&sl[bB + n * 512];
    }
    __builtin_amdgcn_s_setprio(1);
#pragma unroll
    for (int m = 0; m < 8; ++m)
#pragma unroll
      for (int n = 0; n < 4; ++n)
        acc[m][n] = __builtin_amdgcn_mfma_f32_16x16x32_bf16(cA[m], cB[n], acc[m][n], 0, 0, 0);
    __builtin_amdgcn_s_setprio(0);
    __builtin_amdgcn_s_barrier();          // reads of slab p (done last phase,
                                           // lgkm-waited before MFMA) can't
                                           // race STAGE(p+4) next phase
  };

  STAGE(0); STAGE(1); STAGE(2);
  asm volatile("s_waitcnt vmcnt(8)" ::: "memory");   // slab 0 landed
  __builtin_amdgcn_s_barrier();
  {
    const short* sl = &lds[0];
#pragma unroll
    for (int m = 0; m < 8; ++m) fA[m] = *(const short8_t*)&sl[aB + m * 512];
#pragma unroll
    for (int n = 0; n < 4; ++n) fB[n] = *(const short8_t*)&sl[bB + n * 512];
  }

  for (int p = 0; p < NS; p += 2) {
    phase(p,     fA, fB, gA, gB);
    phase(p + 1, gA, gB, fA, fB);
  }

  // ---- epilogue: C/D frag layout col=lane&15, row=kq*4+r ----
#pragma unroll
  for (int m = 0; m < 8; ++m) {
#pragma unroll
    for (int n = 0; n < 4; ++n) {
#pragma unroll
      for (int r = 0; r < 4; ++r) {
        const int gm = m0 + wm + m * 16 + kq * 4 + r;
        const int gn = n0 + wn + n * 16 + fr;
        const float v = acc[m][n][r];
        if constexpr (MODE == 0) {
          short* dst = (short*)Cg;
          const int bh = ((gm >> 11) << 1) + (gn >> 11);
          dst[((size_t)bh << 22) + ((size_t)(gm & 2047) << 11) + (gn & 2047)] = f2bf(v);
        } else if constexpr (MODE == 2) {
          short* dst = (short*)Cg;
          const int bh = ((gm >> 11) << 1) + (gn >> 11);
          dst[((size_t)bh << 22) + ((size_t)(gn & 2047) << 11) + (gm & 2047)] = f2bf(v);
        } else if constexpr (MODE == 3) {
          float* dst = (float*)Cg;
          const float sv = v * 0.022097086912079608f + bias[((z & 1) << 11) + gn];
          dst[((size_t)z << 22) + ((size_t)gm << 11) + gn] = sv;
        } else if constexpr (MODE == 4) {
          short* dst = (short*)Cg;
          const size_t row = ((size_t)(z >> 1) << 11) + gm;
          dst[(row << 12) + ((size_t)(z & 1) << 11) + gn] = f2bf(v);
        } else {
          float* dst = (float*)Cg;
          dst[(size_t)gm * 4096 + gn] = v;
        }
      }
    }
  }
}

// row softmax in place (fp32, 2048 wide) + bf16 copy for the PV GEMM
__global__ __launch_bounds__(256)
void softmax_rows(float* __restrict__ attn, short* __restrict__ outb) {
  float* row  = attn + ((size_t)blockIdx.x << 11);
  short* rowb = outb + ((size_t)blockIdx.x << 11);
  const int tid = threadIdx.x;

  float4 v0 = *(const float4*)(row + tid * 8);
  float4 v1 = *(const float4*)(row + tid * 8 + 4);

  float m = fmaxf(fmaxf(fmaxf(v0.x, v0.y), fmaxf(v0.z, v0.w)),
                  fmaxf(fmaxf(v1.x, v1.y), fmaxf(v1.z, v1.w)));
#pragma unroll
  for (int off = 1; off < 64; off <<= 1) m = fmaxf(m, __shfl_xor(m, off));

  __shared__ float redm[4];
  __shared__ float reds[4];
  if ((tid & 63) == 0) redm[tid >> 6] = m;
  __syncthreads();
  m = fmaxf(fmaxf(redm[0], redm[1]), fmaxf(redm[2], redm[3]));

  float e[8];
  e[0] = expf(v0.x - m); e[1] = expf(v0.y - m); e[2] = expf(v0.z - m); e[3] = expf(v0.w - m);
  e[4] = expf(v1.x - m); e[5] = expf(v1.y - m); e[6] = expf(v1.z - m); e[7] = expf(v1.w - m);
  float s = 0.f;
#pragma unroll
  for (int i = 0; i < 8; ++i) s += e[i];
#pragma unroll
  for (int off = 1; off < 64; off <<= 1) s += __shfl_xor(s, off);
  if ((tid & 63) == 0) reds[tid >> 6] = s;
  __syncthreads();
  s = reds[0] + reds[1] + reds[2] + reds[3];

  const float inv = 1.0f / s;
  float4 o0, o1;
  o0.x = e[0] * inv; o0.y = e[1] * inv; o0.z = e[2] * inv; o0.w = e[3] * inv;
  o1.x = e[4] * inv; o1.y = e[5] * inv; o1.z = e[6] * inv; o1.w = e[7] * inv;
  *(float4*)(row + tid * 8)     = o0;
  *(float4*)(row + tid * 8 + 4) = o1;
  *(short8_t*)(rowb + tid * 8)  = cvt8(o0, o1);
}

extern "C" void kernel_launch(void* const* d_in, const int* in_sizes, int n_in,
                              void* d_out, int out_size, void* d_ws, size_t ws_size,
                              hipStream_t stream) {
  const float* x  = (const float*)d_in[0];
  const float* Wq = (const float*)d_in[1];
  const float* Wk = (const float*)d_in[2];
  const float* Wv = (const float*)d_in[3];
  const float* Wo = (const float*)d_in[4];
  const float* pb = (const float*)d_in[5];

  float* y_out = (float*)d_out;                       // 8*2048*4096 f32
  float* attn  = y_out + (size_t)8 * 2048 * 4096;     // 16*2048*2048 f32

  const size_t NEED = 4ull * 67108864ull * 2ull;      // 512 MB
  if (ws_size < NEED) return;
  short* buf0 = (short*)d_ws;
  short* buf1 = buf0 + 67108864;
  short* buf2 = buf1 + 67108864;
  short* buf3 = buf2 + 67108864;

  short* xb      = buf0;             // x bf16 (16384 x 4096)
  short* qb      = buf1;             // (b,h,t,d)
  short* kb      = buf2;             // (b,h,t,d)
  short* vtb     = buf3;             // (b,h,d,s)
  short* wob     = buf0;             // Wo bf16 (reuses xb after projections)
  short* attn_bf = buf1;             // bf16 probs (reuses qb after scores)
  short* yb      = buf2;             // attn@v bf16 (reuses kb after scores)
  short* wb      = (short*)attn;     // W staging in d_out attn region
                                     // (dead until scores GEMM writes it)

  const dim3 blk512(512);
  const dim3 blk(256);
  const dim3 gcv(2048);
  const dim3 g1k(1024);

  cvt_f32_bf16<<<gcv, blk, 0, stream>>>(x, xb, 67108864 / 8);

  cvt_f32_bf16<<<gcv, blk, 0, stream>>>(Wq, wb, 16777216 / 8);
  gemm256<0><<<g1k, blk512, 0, stream>>>(xb, wb, qb, nullptr);
  cvt_f32_bf16<<<gcv, blk, 0, stream>>>(Wk, wb, 16777216 / 8);
  gemm256<0><<<g1k, blk512, 0, stream>>>(xb, wb, kb, nullptr);
  cvt_f32_bf16<<<gcv, blk, 0, stream>>>(Wv, wb, 16777216 / 8);
  gemm256<2><<<g1k, blk512, 0, stream>>>(xb, wb, vtb, nullptr);

  cvt_f32_bf16<<<gcv, blk, 0, stream>>>(Wo, wob, 16777216 / 8);  // x dead now

  gemm256<3><<<g1k, blk512, 0, stream>>>(qb, kb, attn, pb);
  softmax_rows<<<dim3(32768), blk, 0, stream>>>(attn, attn_bf);
  gemm256<4><<<g1k, blk512, 0, stream>>>(attn_bf, vtb, yb, nullptr);
  gemm256<5><<<g1k, blk512, 0, stream>>>(yb, wob, y_out, nullptr);
}